// Round 5
// baseline (639.314 us; speedup 1.0000x reference)
//
#include <hip/hip_runtime.h>

// Cost volume: left,right [B=2, C=32, H=128, W=256] fp32, max_disp D=32.
// out [B, 2C, D, H, W]:
//   c2 <  C: out = (w+d < W)  ? left [b,c2,  h, w+d] : 0
//   c2 >= C: out = (w-d >= 0) ? right[b,c2-C,h, w-d] : 0
//
// Round-5 structure: one block per OUTPUT PLANE (b, c2, d) -> 4096 blocks.
// Each block writes its 128-KiB [H][W] plane as 32 sequential 4-KiB chunks
// (256 threads x float4) -- a perfectly sequential store stream per block,
// mimicking the 6.3 TB/s fillBuffer pattern (round-4's d-strided scatter
// is the suspected 2.7 TB/s limiter). d is FIXED per block, so each
// thread's 4 clamped gather indices + masks are loop-invariant; only h
// advances. Loads are L1/L2 hits (input plane 128 KiB, reused by the 32
// d-blocks of the same channel); with full unroll all 32 iterations'
// loads are independent -> compiler pipelines them under the store stream.
// All control flow wave-uniform (branch on c2 is per-block).

typedef float vfloat4 __attribute__((ext_vector_type(4)));

__global__ __launch_bounds__(256) void costvol_kernel(
        const float* __restrict__ left,
        const float* __restrict__ right,
        float* __restrict__ out) {
    constexpr int W = 256, H = 128, C = 32;

    const unsigned tid = threadIdx.x;
    const unsigned w4  = tid & 63u;          // float4 position in row
    const unsigned hlo = tid >> 6;           // 0..3

    // bid = d + 32*(c2 + 64*b)  -> matches out memory order exactly.
    const unsigned bid = blockIdx.x;
    const unsigned d   = bid & 31u;
    const unsigned c2  = (bid >> 5) & 63u;
    const unsigned b   = bid >> 11;

    const bool     isL = (c2 < (unsigned)C);
    const unsigned c   = isL ? c2 : (c2 - (unsigned)C);
    const float*   src = isL ? left : right;

    // Input row pointer for h = hlo (advances by 4 rows per iteration).
    const float* row0 = src + ((size_t)(b * C + c) * H + hlo) * W;

    // Loop-invariant clamped indices + masks (depend only on w4, d, side).
    const int base = isL ? (int)(4u * w4 + d) : (int)(4u * w4) - (int)d;
    int  idx[4];
    bool msk[4];
#pragma unroll
    for (int j = 0; j < 4; ++j) {
        int t = base + j;
        msk[j] = isL ? (t < W) : (t >= 0);
        idx[j] = t < 0 ? 0 : (t > W - 1 ? W - 1 : t);
    }

    // Output: plane base = bid * 8192 float4; within plane, iteration it
    // covers h = it*4 + hlo, i.e. float4 offset it*256 + tid. Sequential.
    vfloat4* o = reinterpret_cast<vfloat4*>(out) + (size_t)bid * 8192u + tid;

#pragma unroll
    for (int it = 0; it < 32; ++it) {
        const float* row = row0 + (size_t)it * (4u * W);
        vfloat4 v;
        v.x = msk[0] ? row[idx[0]] : 0.f;
        v.y = msk[1] ? row[idx[1]] : 0.f;
        v.z = msk[2] ? row[idx[2]] : 0.f;
        v.w = msk[3] ? row[idx[3]] : 0.f;
        o[(size_t)it * 256u] = v;
    }
}

extern "C" void kernel_launch(void* const* d_in, const int* in_sizes, int n_in,
                              void* d_out, int out_size, void* d_ws, size_t ws_size,
                              hipStream_t stream) {
    const float* left  = (const float*)d_in[0];
    const float* right = (const float*)d_in[1];
    float* out = (float*)d_out;

    // 4096 blocks x 256 threads x 32 float4 stores = 2^25 float4 = out_size/4.
    costvol_kernel<<<4096, 256, 0, stream>>>(left, right, out);
}